// Round 1
// baseline (101.700 us; speedup 1.0000x reference)
//
#include <hip/hip_runtime.h>

#define N_NODES 8192
#define M_EDGES 2048
#define KK      16
#define QKD     256
#define VD      256
#define NHEAD   8
#define P_PAIRS 120   // 16*15/2
#define CAP     256   // max member edges per node we handle (avg is 4)

// ---------------- Kernel 0: build edge -> node lists from adj ----------------
// adj is (N, M) row-major; coalesced scan, atomics scatter the 32768 memberships.
__global__ void build_edges(const float* __restrict__ adj,
                            int* __restrict__ counts, int* __restrict__ nodes) {
    long long total = (long long)N_NODES * M_EDGES;
    long long stride = (long long)gridDim.x * blockDim.x;
    for (long long i = (long long)blockIdx.x * blockDim.x + threadIdx.x; i < total; i += stride) {
        if (adj[i] > 0.0f) {
            int m = (int)(i % M_EDGES);
            int n = (int)(i / M_EDGES);
            int slot = atomicAdd(&counts[m], 1);
            if (slot < KK) nodes[m * KK + slot] = n;
        }
    }
}

// ---------------- Kernel 1: per-edge weight w[m] ----------------
// Gather 16 member feature vectors, 120 pairwise squared distances,
// sigma = lower median (rank 59), w = sum(exp(-d2/sigma^2)) / 240.
__global__ __launch_bounds__(256) void edge_weights(const float* __restrict__ x1,
                                                    const int* __restrict__ nodes,
                                                    float* __restrict__ w) {
    __shared__ float f[KK][QKD];     // 16 KB
    __shared__ float d2[P_PAIRS];
    __shared__ float ev[P_PAIRS];
    __shared__ float sigma2;
    int m = blockIdx.x;
    int t = threadIdx.x;

    for (int k = 0; k < KK; ++k) {
        int n = nodes[m * KK + k];
        f[k][t] = x1[(long long)n * QKD + t];
    }
    __syncthreads();

    if (t < P_PAIRS) {
        // pair index t -> (i, j), i < j
        int i = 0, p = t;
        while (p >= KK - 1 - i) { p -= KK - 1 - i; ++i; }
        int j = i + 1 + p;
        float acc = 0.0f;
        for (int dd = 0; dd < QKD; ++dd) {
            int d = (dd + t) & (QKD - 1);   // stagger to spread LDS banks
            float diff = f[i][d] - f[j][d];
            acc += diff * diff;
        }
        d2[t] = acc;
    }
    __syncthreads();

    if (t < P_PAIRS) {
        float mine = d2[t];
        int rank = 0;
        for (int q = 0; q < P_PAIRS; ++q) {
            float o = d2[q];
            rank += (o < mine || (o == mine && q < t)) ? 1 : 0;
        }
        if (rank == (P_PAIRS - 1) / 2) sigma2 = mine * mine;  // sigma^2, sigma = median d2
    }
    __syncthreads();

    if (t < P_PAIRS) ev[t] = expf(-d2[t] / sigma2);
    __syncthreads();

    if (t == 0) {
        float s = 0.0f;
        for (int p = 0; p < P_PAIRS; ++p) s += ev[p];
        w[m] = s / (float)(KK * (KK - 1));
    }
}

// ---------------- Kernel 2: mean_vv[d] = (1/M) sum_m w[m] * v[m][d] ----------------
// Needed for nodes with zero member edges (softmax over all-NEG row is uniform).
__global__ void mean_vv_kernel(const float* __restrict__ v, const float* __restrict__ w,
                               float* __restrict__ mean_vv) {
    int t = threadIdx.x;          // d
    int b = blockIdx.x;           // 32 blocks x 64 edges
    float acc = 0.0f;
    for (int mm = 0; mm < M_EDGES / 32; ++mm) {
        int m = b * (M_EDGES / 32) + mm;
        acc += w[m] * v[(long long)m * VD + t];
    }
    atomicAdd(&mean_vv[t], acc * (1.0f / (float)M_EDGES));
}

// ---------------- Kernel 3: per-node sparse attention ----------------
__global__ __launch_bounds__(256) void attn(const float* __restrict__ x1,
                                            const float* __restrict__ x2,
                                            const float* __restrict__ v,
                                            const float* __restrict__ adj,
                                            const float* __restrict__ w,
                                            const float* __restrict__ mean_vv,
                                            float* __restrict__ out) {
    __shared__ int   mem[CAP];
    __shared__ float sc[CAP][NHEAD];    // 8 KB
    __shared__ float inv_sum[NHEAD];
    __shared__ int   wave_off[4];

    int n = blockIdx.x;
    int t = threadIdx.x;
    int lane = t & 63;
    int wv = t >> 6;
    int h = t >> 5;                     // head for this thread (d = t & 31)

    // --- ballot-compact member edges from this node's adj row (ordered, deterministic)
    int base = 0;
    for (int i = 0; i < M_EDGES / 256; ++i) {
        int m = i * 256 + t;
        bool p = adj[(long long)n * M_EDGES + m] > 0.0f;
        unsigned long long mask = __ballot(p);
        if (lane == 0) wave_off[wv] = __popcll(mask);
        __syncthreads();
        int myoff = base;
        for (int ww = 0; ww < wv; ++ww) myoff += wave_off[ww];
        int chunk_total = wave_off[0] + wave_off[1] + wave_off[2] + wave_off[3];
        if (p) {
            int pos = myoff + __popcll(mask & ((1ull << lane) - 1ull));
            if (pos < CAP) mem[pos] = m;
        }
        base += chunk_total;
        __syncthreads();
    }
    int C = min(base, CAP);

    // --- scores: s[c][h] = scale * sum_d q[n,h,d] * k[m,h,d]
    float qv = x1[(long long)n * QKD + t] * 0.17677669529663687f;  // 32^-0.5
    for (int c = 0; c < C; ++c) {
        int m = mem[c];
        float prod = qv * x2[(long long)m * QKD + t];
        prod += __shfl_xor(prod, 16);
        prod += __shfl_xor(prod, 8);
        prod += __shfl_xor(prod, 4);
        prod += __shfl_xor(prod, 2);
        prod += __shfl_xor(prod, 1);
        if ((t & 31) == 0) sc[c][h] = prod;
    }
    __syncthreads();

    // --- per-head softmax over the C member edges (C ~ 4, serial is fine)
    if (t < NHEAD) {
        float mx = -INFINITY;
        for (int c = 0; c < C; ++c) mx = fmaxf(mx, sc[c][t]);
        float s = 0.0f;
        for (int c = 0; c < C; ++c) { float e = expf(sc[c][t] - mx); sc[c][t] = e; s += e; }
        inv_sum[t] = 1.0f / s;
    }
    __syncthreads();

    // --- output: out[n, h*32+d] = (1/sum) * sum_c exp_c * w[m_c] * v[m_c, h*32+d]
    float acc;
    if (C > 0) {
        acc = 0.0f;
        for (int c = 0; c < C; ++c) {
            int m = mem[c];
            acc += sc[c][h] * w[m] * v[(long long)m * VD + t];
        }
        acc *= inv_sum[h];
    } else {
        acc = mean_vv[t];   // uniform softmax over all edges -> mean of w*v
    }
    out[(long long)n * VD + t] = acc;
}

extern "C" void kernel_launch(void* const* d_in, const int* in_sizes, int n_in,
                              void* d_out, int out_size, void* d_ws, size_t ws_size,
                              hipStream_t stream) {
    const float* x1  = (const float*)d_in[0];   // (N, 256)
    const float* x2  = (const float*)d_in[1];   // (M, 256)
    const float* v   = (const float*)d_in[2];   // (M, 256)
    const float* adj = (const float*)d_in[3];   // (N, M)
    float* out = (float*)d_out;                 // (N, 256)

    // workspace layout (floats/ints, all 4-byte):
    float* w       = (float*)d_ws;              // M floats
    float* mean_vv = w + M_EDGES;               // 256 floats
    int*   counts  = (int*)(mean_vv + VD);      // M ints
    int*   nodes   = counts + M_EDGES;          // M*16 ints

    // zero mean_vv + counts (contiguous block)
    hipMemsetAsync(mean_vv, 0, (VD + M_EDGES) * sizeof(float), stream);

    build_edges<<<2048, 256, 0, stream>>>(adj, counts, nodes);
    edge_weights<<<M_EDGES, 256, 0, stream>>>(x1, nodes, w);
    mean_vv_kernel<<<32, 256, 0, stream>>>(v, w, mean_vv);
    attn<<<N_NODES, 256, 0, stream>>>(x1, x2, v, adj, w, mean_vv, out);
}

// Round 2
// 89.589 us; speedup vs baseline: 1.1352x; 1.1352x over previous
//
#include <hip/hip_runtime.h>

#define N_NODES 8192
#define M_EDGES 2048
#define KK      16
#define QKD     256
#define VD      256
#define NHEAD   8
#define P_PAIRS 120   // 16*15/2
#define CAP2    32    // max member edges per node (avg 4, Poisson tail << 32)

// ---------------- Kernel 0: single adj scan -> edge->node AND node->edge lists ----
// adj is (N, M) row-major; float4 loads, branch almost never taken (32768 / 16.7M).
__global__ void build_lists(const float4* __restrict__ adj4,
                            int* __restrict__ ecounts, int* __restrict__ enodes,
                            int* __restrict__ ncounts, int* __restrict__ nedges) {
    const int M4 = M_EDGES / 4;
    int stride = gridDim.x * blockDim.x;
    int total = N_NODES * M4;
    for (int i = blockIdx.x * blockDim.x + threadIdx.x; i < total; i += stride) {
        float4 a = adj4[i];
        if (a.x > 0.f || a.y > 0.f || a.z > 0.f || a.w > 0.f) {
            int n = i / M4;
            int mbase = (i - n * M4) * 4;
            float vals[4] = {a.x, a.y, a.z, a.w};
            #pragma unroll
            for (int j = 0; j < 4; ++j) {
                if (vals[j] > 0.f) {
                    int m = mbase + j;
                    int s1 = atomicAdd(&ecounts[m], 1);
                    if (s1 < KK) enodes[m * KK + s1] = n;
                    int s2 = atomicAdd(&ncounts[n], 1);
                    if (s2 < CAP2) nedges[n * CAP2 + s2] = m;
                }
            }
        }
    }
}

// ---------------- Kernel 1: per-edge weight w[m] ----------------
__global__ __launch_bounds__(256) void edge_weights(const float* __restrict__ x1,
                                                    const int* __restrict__ enodes,
                                                    float* __restrict__ w) {
    __shared__ float f[KK][QKD];       // 16 KB
    __shared__ int   ids[KK];
    __shared__ float part[P_PAIRS][2];
    __shared__ float d2[P_PAIRS];
    __shared__ float sigma2;
    __shared__ float esum[4];
    int m = blockIdx.x;
    int t = threadIdx.x;

    if (t < KK) ids[t] = enodes[m * KK + t];
    __syncthreads();
    if (t == 0) {  // sort ids -> deterministic pair indexing / FP order
        for (int a = 1; a < KK; ++a) {
            int x = ids[a]; int b = a - 1;
            while (b >= 0 && ids[b] > x) { ids[b + 1] = ids[b]; --b; }
            ids[b + 1] = x;
        }
    }
    __syncthreads();
    for (int k = 0; k < KK; ++k) f[k][t] = x1[(long long)ids[k] * QKD + t];
    __syncthreads();

    // pair p handled by 2 threads (half the dims each)
    if (t < 2 * P_PAIRS) {
        int p = t >> 1, hh = t & 1;
        int i = 0, pp = p;
        while (pp >= KK - 1 - i) { pp -= KK - 1 - i; ++i; }
        int j = i + 1 + pp;
        float acc = 0.0f;
        int d0 = hh << 7;
        for (int dd = 0; dd < 128; ++dd) {
            int d = d0 + ((dd + t) & 127);   // stagger banks
            float diff = f[i][d] - f[j][d];
            acc += diff * diff;
        }
        part[p][hh] = acc;
    }
    __syncthreads();
    if (t < P_PAIRS) d2[t] = part[t][0] + part[t][1];
    __syncthreads();

    if (t < P_PAIRS) {   // lower-median rank select (rank 59 of 120)
        float mine = d2[t];
        int rank = 0;
        for (int q = 0; q < P_PAIRS; ++q) {
            float o = d2[q];
            rank += (o < mine || (o == mine && q < t)) ? 1 : 0;
        }
        if (rank == (P_PAIRS - 1) / 2) sigma2 = mine * mine;
    }
    __syncthreads();

    float e = (t < P_PAIRS) ? expf(-d2[t] / sigma2) : 0.0f;
    e += __shfl_xor(e, 32); e += __shfl_xor(e, 16); e += __shfl_xor(e, 8);
    e += __shfl_xor(e, 4);  e += __shfl_xor(e, 2);  e += __shfl_xor(e, 1);
    if ((t & 63) == 0) esum[t >> 6] = e;
    __syncthreads();
    if (t == 0) w[m] = (esum[0] + esum[1] + esum[2] + esum[3]) / (float)(KK * (KK - 1));
}

// ---------------- Kernel 2a/2b: deterministic mean of w[m]*v[m] ----------------
__global__ void mean_vv_part(const float* __restrict__ v, const float* __restrict__ w,
                             float* __restrict__ partials) {
    int t = threadIdx.x, b = blockIdx.x;   // 32 blocks x 64 edges each
    float acc = 0.0f;
    for (int mm = 0; mm < M_EDGES / 32; ++mm) {
        int m = b * (M_EDGES / 32) + mm;
        acc += w[m] * v[(long long)m * VD + t];
    }
    partials[b * VD + t] = acc;
}
__global__ void mean_vv_final(const float* __restrict__ partials, float* __restrict__ mean_vv) {
    int t = threadIdx.x;
    float acc = 0.0f;
    for (int b = 0; b < 32; ++b) acc += partials[b * VD + t];
    mean_vv[t] = acc * (1.0f / (float)M_EDGES);
}

// ---------------- Kernel 3: per-node sparse attention (no adj read) ----------------
__global__ __launch_bounds__(256) void attn(const float* __restrict__ x1,
                                            const float* __restrict__ x2,
                                            const float* __restrict__ v,
                                            const float* __restrict__ w,
                                            const int* __restrict__ ncounts,
                                            const int* __restrict__ nedges,
                                            const float* __restrict__ mean_vv,
                                            float* __restrict__ out) {
    __shared__ int   mem[CAP2];
    __shared__ float sc[CAP2][NHEAD];
    __shared__ float inv_sum[NHEAD];

    int n = blockIdx.x;
    int t = threadIdx.x;
    int h = t >> 5;

    int C = ncounts[n]; if (C > CAP2) C = CAP2;
    if (t < C) mem[t] = nedges[n * CAP2 + t];
    __syncthreads();
    if (t == 0 && C > 1) {   // sort -> deterministic softmax order
        for (int a = 1; a < C; ++a) {
            int x = mem[a]; int b = a - 1;
            while (b >= 0 && mem[b] > x) { mem[b + 1] = mem[b]; --b; }
            mem[b + 1] = x;
        }
    }
    __syncthreads();

    float qv = x1[(long long)n * QKD + t] * 0.17677669529663687f;  // 32^-0.5
    for (int c = 0; c < C; ++c) {
        int m = mem[c];
        float prod = qv * x2[(long long)m * QKD + t];
        prod += __shfl_xor(prod, 16);
        prod += __shfl_xor(prod, 8);
        prod += __shfl_xor(prod, 4);
        prod += __shfl_xor(prod, 2);
        prod += __shfl_xor(prod, 1);
        if ((t & 31) == 0) sc[c][h] = prod;
    }
    __syncthreads();

    if (t < NHEAD) {
        float mx = -INFINITY;
        for (int c = 0; c < C; ++c) mx = fmaxf(mx, sc[c][t]);
        float s = 0.0f;
        for (int c = 0; c < C; ++c) { float e = expf(sc[c][t] - mx); sc[c][t] = e; s += e; }
        inv_sum[t] = 1.0f / s;
    }
    __syncthreads();

    float acc;
    if (C > 0) {
        acc = 0.0f;
        for (int c = 0; c < C; ++c) {
            int m = mem[c];
            acc += sc[c][h] * w[m] * v[(long long)m * VD + t];
        }
        acc *= inv_sum[h];
    } else {
        acc = mean_vv[t];   // empty row: softmax over all-NEG is uniform -> mean of w*v
    }
    out[(long long)n * VD + t] = acc;
}

extern "C" void kernel_launch(void* const* d_in, const int* in_sizes, int n_in,
                              void* d_out, int out_size, void* d_ws, size_t ws_size,
                              hipStream_t stream) {
    const float* x1  = (const float*)d_in[0];   // (N, 256)
    const float* x2  = (const float*)d_in[1];   // (M, 256)
    const float* v   = (const float*)d_in[2];   // (M, 256)
    const float* adj = (const float*)d_in[3];   // (N, M)
    float* out = (float*)d_out;                 // (N, 256)

    // workspace layout (all 4-byte elems), ~1.26 MB total
    float* w        = (float*)d_ws;             // M
    float* mean_vv  = w + M_EDGES;              // VD
    float* partials = mean_vv + VD;             // 32*VD
    int*   ecounts  = (int*)(partials + 32 * VD); // M
    int*   ncounts  = ecounts + M_EDGES;        // N
    int*   enodes   = ncounts + N_NODES;        // M*KK
    int*   nedges   = enodes + M_EDGES * KK;    // N*CAP2

    hipMemsetAsync(ecounts, 0, (M_EDGES + N_NODES) * sizeof(int), stream);

    build_lists<<<2048, 256, 0, stream>>>((const float4*)adj, ecounts, enodes, ncounts, nedges);
    edge_weights<<<M_EDGES, 256, 0, stream>>>(x1, enodes, w);
    mean_vv_part<<<32, 256, 0, stream>>>(v, w, partials);
    mean_vv_final<<<1, 256, 0, stream>>>(partials, mean_vv);
    attn<<<N_NODES, 256, 0, stream>>>(x1, x2, v, w, ncounts, nedges, mean_vv, out);
}

// Round 3
// 84.931 us; speedup vs baseline: 1.1974x; 1.0548x over previous
//
#include <hip/hip_runtime.h>

#define N_NODES 8192
#define M_EDGES 2048
#define KK      16
#define QKD     256
#define VD      256
#define NHEAD   8
#define P_PAIRS 120   // 16*15/2
#define CAP2    32    // max member edges per node (avg 4)
#define FSTRIDE (QKD + 4)   // padded LDS row stride (floats) -> rotates bank groups per row

// ---------------- Kernel Z: zero the two count arrays (NOT hipMemsetAsync: the
// rocclr fill kernel costs ~40us for 40KB; this costs ~2us) ----------------
__global__ void zero_counts(int* __restrict__ p) {
    int i = blockIdx.x * blockDim.x + threadIdx.x;
    if (i < M_EDGES + N_NODES) p[i] = 0;
}

// ---------------- Kernel 0: single adj scan -> edge->node AND node->edge lists ----
__global__ void build_lists(const float4* __restrict__ adj4,
                            int* __restrict__ ecounts, int* __restrict__ enodes,
                            int* __restrict__ ncounts, int* __restrict__ nedges) {
    const int M4 = M_EDGES / 4;           // 512 (pow2 -> div is a shift)
    int stride = gridDim.x * blockDim.x;
    int total = N_NODES * M4;
    for (int i = blockIdx.x * blockDim.x + threadIdx.x; i < total; i += stride) {
        float4 a = adj4[i];
        if (a.x > 0.f || a.y > 0.f || a.z > 0.f || a.w > 0.f) {
            int n = i / M4;
            int mbase = (i - n * M4) * 4;
            float vals[4] = {a.x, a.y, a.z, a.w};
            #pragma unroll
            for (int j = 0; j < 4; ++j) {
                if (vals[j] > 0.f) {
                    int m = mbase + j;
                    int s1 = atomicAdd(&ecounts[m], 1);
                    if (s1 < KK) enodes[m * KK + s1] = n;
                    int s2 = atomicAdd(&ncounts[n], 1);
                    if (s2 < CAP2) nedges[n * CAP2 + s2] = m;
                }
            }
        }
    }
}

// ---------------- Kernel 1: per-edge weight w[m] ----------------
__global__ __launch_bounds__(256) void edge_weights(const float* __restrict__ x1,
                                                    const int* __restrict__ enodes,
                                                    float* __restrict__ w) {
    __shared__ float f[KK][FSTRIDE];   // padded: row k starts at bank (4k)%32
    __shared__ int   ids[KK];
    __shared__ float part[P_PAIRS][2];
    __shared__ float d2[P_PAIRS];
    __shared__ float sigma2;
    __shared__ float esum[4];
    int m = blockIdx.x;
    int t = threadIdx.x;

    if (t < KK) ids[t] = enodes[m * KK + t];
    __syncthreads();
    if (t == 0) {  // sort ids -> deterministic FP order regardless of atomic order
        for (int a = 1; a < KK; ++a) {
            int x = ids[a]; int b = a - 1;
            while (b >= 0 && ids[b] > x) { ids[b + 1] = ids[b]; --b; }
            ids[b + 1] = x;
        }
    }
    __syncthreads();
    for (int k = 0; k < KK; ++k) f[k][t] = x1[(long long)ids[k] * QKD + t];
    __syncthreads();

    // pair p handled by 2 threads (half the dims each), float4 LDS reads
    if (t < 2 * P_PAIRS) {
        int p = t >> 1, hh = t & 1;
        int i = 0, pp = p;
        while (pp >= KK - 1 - i) { pp -= KK - 1 - i; ++i; }
        int j = i + 1 + pp;
        const float4* fi = (const float4*)&f[i][0];
        const float4* fj = (const float4*)&f[j][0];
        int base4 = hh << 5;              // 32 float4s per half
        float acc = 0.0f;
        #pragma unroll 4
        for (int dd = 0; dd < 32; ++dd) {
            int d4 = base4 + ((dd + t) & 31);   // lane-stagger
            float4 a = fi[d4], b = fj[d4];
            float dx = a.x - b.x, dy = a.y - b.y, dz = a.z - b.z, dw = a.w - b.w;
            acc += dx * dx + dy * dy + dz * dz + dw * dw;
        }
        part[p][hh] = acc;
    }
    __syncthreads();
    if (t < P_PAIRS) d2[t] = part[t][0] + part[t][1];
    __syncthreads();

    if (t < P_PAIRS) {   // lower-median rank select (rank 59 of 120)
        float mine = d2[t];
        int rank = 0;
        for (int q = 0; q < P_PAIRS; ++q) {
            float o = d2[q];
            rank += (o < mine || (o == mine && q < t)) ? 1 : 0;
        }
        if (rank == (P_PAIRS - 1) / 2) sigma2 = mine * mine;
    }
    __syncthreads();

    float e = (t < P_PAIRS) ? expf(-d2[t] / sigma2) : 0.0f;
    e += __shfl_xor(e, 32); e += __shfl_xor(e, 16); e += __shfl_xor(e, 8);
    e += __shfl_xor(e, 4);  e += __shfl_xor(e, 2);  e += __shfl_xor(e, 1);
    if ((t & 63) == 0) esum[t >> 6] = e;
    __syncthreads();
    if (t == 0) w[m] = (esum[0] + esum[1] + esum[2] + esum[3]) / (float)(KK * (KK - 1));
}

// ---------------- Kernel 2a/2b: deterministic mean of w[m]*v[m] ----------------
__global__ void mean_vv_part(const float* __restrict__ v, const float* __restrict__ w,
                             float* __restrict__ partials) {
    int t = threadIdx.x, b = blockIdx.x;   // 32 blocks x 64 edges each
    float acc = 0.0f;
    for (int mm = 0; mm < M_EDGES / 32; ++mm) {
        int m = b * (M_EDGES / 32) + mm;
        acc += w[m] * v[(long long)m * VD + t];
    }
    partials[b * VD + t] = acc;
}
__global__ void mean_vv_final(const float* __restrict__ partials, float* __restrict__ mean_vv) {
    int t = threadIdx.x;
    float acc = 0.0f;
    for (int b = 0; b < 32; ++b) acc += partials[b * VD + t];
    mean_vv[t] = acc * (1.0f / (float)M_EDGES);
}

// ---------------- Kernel 3: per-node sparse attention (no adj read) ----------------
__global__ __launch_bounds__(256) void attn(const float* __restrict__ x1,
                                            const float* __restrict__ x2,
                                            const float* __restrict__ v,
                                            const float* __restrict__ w,
                                            const int* __restrict__ ncounts,
                                            const int* __restrict__ nedges,
                                            const float* __restrict__ mean_vv,
                                            float* __restrict__ out) {
    __shared__ int   mem[CAP2];
    __shared__ float sc[CAP2][NHEAD];
    __shared__ float inv_sum[NHEAD];

    int n = blockIdx.x;
    int t = threadIdx.x;
    int h = t >> 5;

    int C = ncounts[n]; if (C > CAP2) C = CAP2;
    if (t < C) mem[t] = nedges[n * CAP2 + t];
    __syncthreads();
    if (t == 0 && C > 1) {   // sort -> deterministic softmax order
        for (int a = 1; a < C; ++a) {
            int x = mem[a]; int b = a - 1;
            while (b >= 0 && mem[b] > x) { mem[b + 1] = mem[b]; --b; }
            mem[b + 1] = x;
        }
    }
    __syncthreads();

    float qv = x1[(long long)n * QKD + t] * 0.17677669529663687f;  // 32^-0.5
    for (int c = 0; c < C; ++c) {
        int m = mem[c];
        float prod = qv * x2[(long long)m * QKD + t];
        prod += __shfl_xor(prod, 16);
        prod += __shfl_xor(prod, 8);
        prod += __shfl_xor(prod, 4);
        prod += __shfl_xor(prod, 2);
        prod += __shfl_xor(prod, 1);
        if ((t & 31) == 0) sc[c][h] = prod;
    }
    __syncthreads();

    if (t < NHEAD) {
        float mx = -INFINITY;
        for (int c = 0; c < C; ++c) mx = fmaxf(mx, sc[c][t]);
        float s = 0.0f;
        for (int c = 0; c < C; ++c) { float e = expf(sc[c][t] - mx); sc[c][t] = e; s += e; }
        inv_sum[t] = 1.0f / s;
    }
    __syncthreads();

    float acc;
    if (C > 0) {
        acc = 0.0f;
        for (int c = 0; c < C; ++c) {
            int m = mem[c];
            acc += sc[c][h] * w[m] * v[(long long)m * VD + t];
        }
        acc *= inv_sum[h];
    } else {
        acc = mean_vv[t];   // empty row: softmax over all-NEG is uniform -> mean of w*v
    }
    out[(long long)n * VD + t] = acc;
}

extern "C" void kernel_launch(void* const* d_in, const int* in_sizes, int n_in,
                              void* d_out, int out_size, void* d_ws, size_t ws_size,
                              hipStream_t stream) {
    const float* x1  = (const float*)d_in[0];   // (N, 256)
    const float* x2  = (const float*)d_in[1];   // (M, 256)
    const float* v   = (const float*)d_in[2];   // (M, 256)
    const float* adj = (const float*)d_in[3];   // (N, M)
    float* out = (float*)d_out;                 // (N, 256)

    // workspace layout (all 4-byte elems), ~1.2 MB total
    float* w        = (float*)d_ws;             // M
    float* mean_vv  = w + M_EDGES;              // VD
    float* partials = mean_vv + VD;             // 32*VD
    int*   ecounts  = (int*)(partials + 32 * VD); // M   } zeroed together
    int*   ncounts  = ecounts + M_EDGES;        // N    }
    int*   enodes   = ncounts + N_NODES;        // M*KK
    int*   nedges   = enodes + M_EDGES * KK;    // N*CAP2

    zero_counts<<<(M_EDGES + N_NODES + 255) / 256, 256, 0, stream>>>(ecounts);
    build_lists<<<2048, 256, 0, stream>>>((const float4*)adj, ecounts, enodes, ncounts, nedges);
    edge_weights<<<M_EDGES, 256, 0, stream>>>(x1, enodes, w);
    mean_vv_part<<<32, 256, 0, stream>>>(v, w, partials);
    mean_vv_final<<<1, 256, 0, stream>>>(partials, mean_vv);
    attn<<<N_NODES, 256, 0, stream>>>(x1, x2, v, w, ncounts, nedges, mean_vv, out);
}

// Round 4
// 81.489 us; speedup vs baseline: 1.2480x; 1.0422x over previous
//
#include <hip/hip_runtime.h>

#define N_NODES 8192
#define M_EDGES 2048
#define KK      16
#define QKD     256
#define VD      256
#define NHEAD   8
#define P_PAIRS 120   // 16*15/2
#define CAP2    32    // max member edges per node (avg 4)
#define NPART   32    // mean-reduction partial blocks
#define FSTRIDE (QKD + 4)   // padded LDS row stride (floats)

// ---------------- K0: zero ecounts (8 KB) — NOT hipMemsetAsync/fill ----------------
__global__ void zero_counts(int* __restrict__ p) {
    int i = blockIdx.x * blockDim.x + threadIdx.x;
    if (i < M_EDGES) p[i] = 0;
}

// ---------------- K1: wave-per-row ballot scan of adj ----------------
// One wave64 per node row: 8 chunks x 64 lanes x float4 (coalesced 1KB/instr).
// Ballot-compact member edges in ASCENDING m order -> nedges deterministic,
// no atomics on the node side. Edge side keeps atomics (sorted later).
__global__ __launch_bounds__(256) void scan_adj(const float4* __restrict__ adj4,
                                                int* __restrict__ ecounts,
                                                int* __restrict__ enodes,
                                                int* __restrict__ ncounts,
                                                int* __restrict__ nedges) {
    int wid  = (blockIdx.x * blockDim.x + threadIdx.x) >> 6;   // node id
    int lane = threadIdx.x & 63;
    if (wid >= N_NODES) return;
    const float4* row = adj4 + (long long)wid * (M_EDGES / 4);
    unsigned long long below = (1ull << lane) - 1ull;   // lane<64, lane=63 ok
    int base = 0;
    #pragma unroll
    for (int c = 0; c < M_EDGES / 4 / 64; ++c) {        // 8 chunks
        float4 a = row[c * 64 + lane];
        unsigned long long b0 = __ballot(a.x > 0.f);
        unsigned long long b1 = __ballot(a.y > 0.f);
        unsigned long long b2 = __ballot(a.z > 0.f);
        unsigned long long b3 = __ballot(a.w > 0.f);
        if ((b0 | b1 | b2 | b3) != 0ull) {
            int pre = __popcll(b0 & below) + __popcll(b1 & below)
                    + __popcll(b2 & below) + __popcll(b3 & below);
            int mbase = (c * 64 + lane) * 4;
            float vals[4] = {a.x, a.y, a.z, a.w};
            int own = 0;
            #pragma unroll
            for (int j = 0; j < 4; ++j) {
                if (vals[j] > 0.f) {
                    int m = mbase + j;
                    int pos = base + pre + own;         // ascending-m position
                    if (pos < CAP2) nedges[wid * CAP2 + pos] = m;
                    int slot = atomicAdd(&ecounts[m], 1);
                    if (slot < KK) enodes[m * KK + slot] = wid;
                    ++own;
                }
            }
        }
        base += __popcll(b0) + __popcll(b1) + __popcll(b2) + __popcll(b3);
    }
    if (lane == 0) ncounts[wid] = base;
}

// ---------------- K2: per-edge weight w[m] ----------------
__global__ __launch_bounds__(256) void edge_weights(const float* __restrict__ x1,
                                                    const int* __restrict__ enodes,
                                                    float* __restrict__ w) {
    __shared__ float f[KK][FSTRIDE];
    __shared__ int   ids[KK];
    __shared__ float part[P_PAIRS][2];
    __shared__ float d2[P_PAIRS];
    __shared__ float sigma2;
    __shared__ float esum[4];
    int m = blockIdx.x;
    int t = threadIdx.x;

    if (t < KK) ids[t] = enodes[m * KK + t];
    __syncthreads();
    if (t == 0) {  // sort -> deterministic order regardless of atomic scatter
        for (int a = 1; a < KK; ++a) {
            int x = ids[a]; int b = a - 1;
            while (b >= 0 && ids[b] > x) { ids[b + 1] = ids[b]; --b; }
            ids[b + 1] = x;
        }
    }
    __syncthreads();
    for (int k = 0; k < KK; ++k) f[k][t] = x1[(long long)ids[k] * QKD + t];
    __syncthreads();

    // pair p split across 2 threads (128 dims each), float4 LDS reads
    if (t < 2 * P_PAIRS) {
        int p = t >> 1, hh = t & 1;
        int i = 0, pp = p;
        while (pp >= KK - 1 - i) { pp -= KK - 1 - i; ++i; }
        int j = i + 1 + pp;
        const float4* fi = (const float4*)&f[i][0];
        const float4* fj = (const float4*)&f[j][0];
        int base4 = hh << 5;
        float acc = 0.0f;
        #pragma unroll 4
        for (int dd = 0; dd < 32; ++dd) {
            int d4 = base4 + ((dd + t) & 31);
            float4 a = fi[d4], b = fj[d4];
            float dx = a.x - b.x, dy = a.y - b.y, dz = a.z - b.z, dw = a.w - b.w;
            acc += dx * dx + dy * dy + dz * dz + dw * dw;
        }
        part[p][hh] = acc;
    }
    __syncthreads();
    if (t < P_PAIRS) d2[t] = part[t][0] + part[t][1];
    __syncthreads();

    if (t < P_PAIRS) {   // lower-median rank select (rank 59 of 120)
        float mine = d2[t];
        int rank = 0;
        for (int q = 0; q < P_PAIRS; ++q) {
            float o = d2[q];
            rank += (o < mine || (o == mine && q < t)) ? 1 : 0;
        }
        if (rank == (P_PAIRS - 1) / 2) sigma2 = mine * mine;
    }
    __syncthreads();

    float e = (t < P_PAIRS) ? expf(-d2[t] / sigma2) : 0.0f;
    e += __shfl_xor(e, 32); e += __shfl_xor(e, 16); e += __shfl_xor(e, 8);
    e += __shfl_xor(e, 4);  e += __shfl_xor(e, 2);  e += __shfl_xor(e, 1);
    if ((t & 63) == 0) esum[t >> 6] = e;
    __syncthreads();
    if (t == 0) w[m] = (esum[0] + esum[1] + esum[2] + esum[3]) / (float)(KK * (KK - 1));
}

// ---------------- K3: partial sums of w[m]*v[m] (deterministic) ----------------
__global__ void mean_vv_part(const float* __restrict__ v, const float* __restrict__ w,
                             float* __restrict__ partials) {
    int t = threadIdx.x, b = blockIdx.x;   // 32 blocks x 64 edges each
    float acc = 0.0f;
    for (int mm = 0; mm < M_EDGES / NPART; ++mm) {
        int m = b * (M_EDGES / NPART) + mm;
        acc += w[m] * v[(long long)m * VD + t];
    }
    partials[b * VD + t] = acc;
}

// ---------------- K4: per-node sparse attention ----------------
__global__ __launch_bounds__(256) void attn(const float* __restrict__ x1,
                                            const float* __restrict__ x2,
                                            const float* __restrict__ v,
                                            const float* __restrict__ w,
                                            const int* __restrict__ ncounts,
                                            const int* __restrict__ nedges,
                                            const float* __restrict__ partials,
                                            float* __restrict__ out) {
    __shared__ int   mem[CAP2];
    __shared__ float sc[CAP2][NHEAD];
    __shared__ float inv_sum[NHEAD];

    int n = blockIdx.x;
    int t = threadIdx.x;
    int h = t >> 5;

    int C = ncounts[n]; if (C > CAP2) C = CAP2;
    if (t < C) mem[t] = nedges[n * CAP2 + t];   // already ascending (ballot order)
    __syncthreads();

    float qv = x1[(long long)n * QKD + t] * 0.17677669529663687f;  // 32^-0.5
    for (int c = 0; c < C; ++c) {
        int m = mem[c];
        float prod = qv * x2[(long long)m * QKD + t];
        prod += __shfl_xor(prod, 16);
        prod += __shfl_xor(prod, 8);
        prod += __shfl_xor(prod, 4);
        prod += __shfl_xor(prod, 2);
        prod += __shfl_xor(prod, 1);
        if ((t & 31) == 0) sc[c][h] = prod;
    }
    __syncthreads();

    if (t < NHEAD) {
        float mx = -INFINITY;
        for (int c = 0; c < C; ++c) mx = fmaxf(mx, sc[c][t]);
        float s = 0.0f;
        for (int c = 0; c < C; ++c) { float e = expf(sc[c][t] - mx); sc[c][t] = e; s += e; }
        inv_sum[t] = 1.0f / s;
    }
    __syncthreads();

    float acc;
    if (C > 0) {
        acc = 0.0f;
        for (int c = 0; c < C; ++c) {
            int m = mem[c];
            acc += sc[c][h] * w[m] * v[(long long)m * VD + t];
        }
        acc *= inv_sum[h];
    } else {
        // empty row: softmax over all-NEG is uniform -> mean of w*v (reduce partials)
        float s = 0.0f;
        #pragma unroll
        for (int b = 0; b < NPART; ++b) s += partials[b * VD + t];
        acc = s * (1.0f / (float)M_EDGES);
    }
    out[(long long)n * VD + t] = acc;
}

extern "C" void kernel_launch(void* const* d_in, const int* in_sizes, int n_in,
                              void* d_out, int out_size, void* d_ws, size_t ws_size,
                              hipStream_t stream) {
    const float* x1  = (const float*)d_in[0];   // (N, 256)
    const float* x2  = (const float*)d_in[1];   // (M, 256)
    const float* v   = (const float*)d_in[2];   // (M, 256)
    const float* adj = (const float*)d_in[3];   // (N, M)
    float* out = (float*)d_out;                 // (N, 256)

    // workspace layout (all 4-byte elems), ~1.2 MB total
    float* w        = (float*)d_ws;               // M
    float* partials = w + M_EDGES;                // NPART*VD
    int*   ecounts  = (int*)(partials + NPART * VD); // M (zeroed)
    int*   ncounts  = ecounts + M_EDGES;          // N (written directly)
    int*   enodes   = ncounts + N_NODES;          // M*KK
    int*   nedges   = enodes + M_EDGES * KK;      // N*CAP2

    zero_counts<<<(M_EDGES + 255) / 256, 256, 0, stream>>>(ecounts);
    scan_adj<<<N_NODES / 4, 256, 0, stream>>>((const float4*)adj, ecounts, enodes, ncounts, nedges);
    edge_weights<<<M_EDGES, 256, 0, stream>>>(x1, enodes, w);
    mean_vv_part<<<NPART, 256, 0, stream>>>(v, w, partials);
    attn<<<N_NODES, 256, 0, stream>>>(x1, x2, v, w, ncounts, nedges, partials, out);
}